// Round 3
// baseline (284.263 us; speedup 1.0000x reference)
//
#include <hip/hip_runtime.h>
#include <hip/hip_bf16.h>

// StyleGAN3 filtered_lrelu, fused; bf16 LDS for the big intermediate (zs),
// sliding-window tasks to cut DS instruction count.
//
// Math (identical to verified R1/R2 kernels):
//   fk[t] = f[11-t]
//   up (per axis, gain 2): out idx i: base=i>>1, tap0=1-(i&1):
//       v[i] = 2 * sum_{s<6} fk[2s+tap0] * src[base+s]
//   leaky relu slope 0.01 between up and down
//   down (per axis): out[o] = sum_{t<12} fk[t] * z[2o+t]
//
// Tile 32x32 out / block, 256 threads. LDS (dwords):
//   XS [42][44] f32 @0      (halo, dead after A)
//   VS [74][44] f32 @1848   (vert-up, dead after B)
//   WS [32][84] f32 @1848   (vert-down, overlays VS)
//   ZS [74][40] bf16x2 @5104 (up+lrelu result; cols>=74 garbage, never consumed)
// total 8064 dw = 31.5 KB -> 5 blocks/CU.

#define TAPS 12
#define XS 0
#define XSS 44
#define VS 1848
#define VSS 44
#define WS 1848
#define WSS 84
#define ZS 5104
#define ZSS 40
#define LDS_DW 8064

__device__ __forceinline__ float bl(unsigned u){ return __uint_as_float(u << 16); }
__device__ __forceinline__ float bh(unsigned u){ return __uint_as_float(u & 0xffff0000u); }
__device__ __forceinline__ unsigned pk_bf2(float lo, float hi){
    __hip_bfloat16 a = __float2bfloat16(lo), b = __float2bfloat16(hi);
    unsigned short ua, ub;
    __builtin_memcpy(&ua, &a, 2); __builtin_memcpy(&ub, &b, 2);
    return (unsigned)ua | ((unsigned)ub << 16);
}

__global__ __launch_bounds__(256, 5) void flrelu_fused(
    const float* __restrict__ x, const float* __restrict__ f, float* __restrict__ out)
{
    __shared__ float smem[LDS_DW];
    unsigned* smemu = reinterpret_cast<unsigned*>(smem);

    const int tid = threadIdx.x;
    const int nc  = blockIdx.y;
    const int ho0 = (blockIdx.x >> 2) * 32;
    const int wo0 = (blockIdx.x & 3) * 32;

    float fk[TAPS];
#pragma unroll
    for (int t = 0; t < TAPS; ++t) fk[t] = f[TAPS - 1 - t];

    const float* xin = x + (size_t)nc * (128 * 128);

    // ---- halo load: 42x42 fp32 ----
#pragma unroll
    for (int k = 0; k < 7; ++k) {
        int e = tid + 256 * k;
        if (e < 42 * 42) {
            int r = e / 42, c = e - r * 42;
            int gr = ho0 - 5 + r, gc = wo0 - 5 + c;
            float v = 0.f;
            if ((unsigned)gr < 128u && (unsigned)gc < 128u) v = xin[gr * 128 + gc];
            smem[XS + r * XSS + c] = v;
        }
    }
    __syncthreads();

    // ---- A: vertical up (fp32 -> VS). task = (col-pair cp<21, m-chunk mc<10), m=4mc+k ----
    if (tid < 210) {
        int cp = tid % 21, mc = tid / 21;
        int m0 = mc * 4;
        float2 v[9];
#pragma unroll
        for (int s = 0; s < 9; ++s) {
            int r = m0 + s; r = r < 42 ? r : 41;      // clamp; clamped rows only feed skipped m
            v[s] = *(const float2*)(smem + XS + r * XSS + 2 * cp);
        }
#pragma unroll
        for (int k = 0; k < 4; ++k) {
            int m = m0 + k;
            if (m < 37) {
                float ex = 0.f, ey = 0.f, ox = 0.f, oy = 0.f;
#pragma unroll
                for (int s = 0; s < 6; ++s) {
                    ex += fk[2*s+1] * v[k+s].x;  ey += fk[2*s+1] * v[k+s].y;
                    ox += fk[2*s]   * v[k+s].x;  oy += fk[2*s]   * v[k+s].y;
                }
                *(float2*)(smem + VS + (2*m)   * VSS + 2*cp) = make_float2(2.f*ex, 2.f*ey);
                *(float2*)(smem + VS + (2*m+1) * VSS + 2*cp) = make_float2(2.f*ox, 2.f*oy);
            }
        }
    }
    __syncthreads();

    // ---- B: horizontal up + lrelu (VS -> ZS bf16). task = (row i<74, 16-col chunk q<5) ----
#pragma unroll
    for (int it = 0; it < 2; ++it) {
        int task = tid + 256 * it;
        if (task < 370) {
            int q = task % 5, i = task / 5;
            const float* vp = smem + VS + i * VSS + 8 * q;
            float4 a  = *(const float4*)(vp);
            float4 b  = *(const float4*)(vp + 4);
            float4 cc = *(const float4*)(vp + 8);
            float c12 = vp[12];
            float c[13] = { a.x,a.y,a.z,a.w, b.x,b.y,b.z,b.w, cc.x,cc.y,cc.z,cc.w, c12 };
            unsigned pkz[8];
#pragma unroll
            for (int h = 0; h < 8; ++h) {            // j = 16q+2h (even), 16q+2h+1 (odd)
                float ze = 0.f, zo = 0.f;
#pragma unroll
                for (int s = 0; s < 6; ++s) {
                    ze += fk[2*s+1] * c[h+s];
                    zo += fk[2*s]   * c[h+s];
                }
                ze *= 2.f; zo *= 2.f;
                ze = ze >= 0.f ? ze : 0.01f * ze;
                zo = zo >= 0.f ? zo : 0.01f * zo;
                pkz[h] = pk_bf2(ze, zo);
            }
            unsigned* zp = smemu + ZS + i * ZSS + 8 * q;
            *(uint4*)(zp)     = make_uint4(pkz[0], pkz[1], pkz[2], pkz[3]);
            *(uint4*)(zp + 4) = make_uint4(pkz[4], pkz[5], pkz[6], pkz[7]);
        }
    }
    __syncthreads();

    // ---- C: vertical down (ZS -> WS fp32). task = (col-oct p8<10, ho-chunk hc<16) on tid>=96 ----
    if (tid >= 96) {
        int t2 = tid - 96;
        int p8 = t2 % 10, hc = t2 / 10;
        const unsigned* zp = smemu + ZS + (4 * hc) * ZSS + 4 * p8;
        float a0[8] = {0,0,0,0,0,0,0,0}, a1[8] = {0,0,0,0,0,0,0,0};
#pragma unroll
        for (int u = 0; u < 14; ++u) {
            uint4 zr = *(const uint4*)(zp + u * ZSS);
            float zv[8] = { bl(zr.x), bh(zr.x), bl(zr.y), bh(zr.y),
                            bl(zr.z), bh(zr.z), bl(zr.w), bh(zr.w) };
            if (u < 12) {
                float w = fk[u];
#pragma unroll
                for (int e = 0; e < 8; ++e) a0[e] += w * zv[e];
            }
            if (u >= 2) {
                float w = fk[u - 2];
#pragma unroll
                for (int e = 0; e < 8; ++e) a1[e] += w * zv[e];
            }
        }
        float* wp = smem + WS + (2 * hc) * WSS + 8 * p8;
        *(float4*)(wp)           = make_float4(a0[0], a0[1], a0[2], a0[3]);
        *(float4*)(wp + 4)       = make_float4(a0[4], a0[5], a0[6], a0[7]);
        *(float4*)(wp + WSS)     = make_float4(a1[0], a1[1], a1[2], a1[3]);
        *(float4*)(wp + WSS + 4) = make_float4(a1[4], a1[5], a1[6], a1[7]);
    }
    __syncthreads();

    // ---- D: horizontal down (WS -> global). task = (ho = tid>>3, col-quad w4 = tid&7) ----
    {
        int ho = tid >> 3, w4 = tid & 7;
        const float* wp = smem + WS + ho * WSS + 8 * w4;
        float4 r0 = *(const float4*)(wp);
        float4 r1 = *(const float4*)(wp + 4);
        float4 r2 = *(const float4*)(wp + 8);
        float4 r3 = *(const float4*)(wp + 12);
        float2 r4 = *(const float2*)(wp + 16);
        float w[18] = { r0.x,r0.y,r0.z,r0.w, r1.x,r1.y,r1.z,r1.w,
                        r2.x,r2.y,r2.z,r2.w, r3.x,r3.y,r3.z,r3.w, r4.x,r4.y };
        float o[4];
#pragma unroll
        for (int v = 0; v < 4; ++v) {
            float acc = 0.f;
#pragma unroll
            for (int t = 0; t < TAPS; ++t) acc += fk[t] * w[2 * v + t];
            o[v] = acc;
        }
        *(float4*)(out + ((size_t)nc * 128 + (ho0 + ho)) * 128 + wo0 + 4 * w4)
            = make_float4(o[0], o[1], o[2], o[3]);
    }
}

extern "C" void kernel_launch(void* const* d_in, const int* in_sizes, int n_in,
                              void* d_out, int out_size, void* d_ws, size_t ws_size,
                              hipStream_t stream) {
    const float* x = (const float*)d_in[0];
    const float* f = (const float*)d_in[1];
    float* out = (float*)d_out;
    dim3 grid(16, 1024);
    flrelu_fused<<<grid, 256, 0, stream>>>(x, f, out);
}

// Round 4
// 111.998 us; speedup vs baseline: 2.5381x; 2.5381x over previous
//
#include <hip/hip_runtime.h>
#include <hip/hip_bf16.h>

// StyleGAN3 filtered_lrelu, fused; bf16 LDS for the big intermediate (zs),
// sliding-window tasks to cut DS instruction count. No launch_bounds min-wave
// arg (R3's ",5" caused a VGPR cap -> scratch spill -> 2x regression).
//
// Math (identical to verified R1/R2/R3 kernels):
//   fk[t] = f[11-t]
//   up (per axis, gain 2): out idx i: base=i>>1, tap0=1-(i&1):
//       v[i] = 2 * sum_{s<6} fk[2s+tap0] * src[base+s]
//   leaky relu slope 0.01 between up and down
//   down (per axis): out[o] = sum_{t<12} fk[t] * z[2o+t]
//
// Tile 32x32 out / block, 256 threads. LDS (dwords):
//   XS [42][44] f32 @0      (halo, dead after A)
//   VS [74][44] f32 @1848   (vert-up, dead after B)
//   WS [32][84] f32 @1848   (vert-down, overlays VS; 1848+2688 <= 5104 ok)
//   ZS [74][40] bf16x2 @5104 (up+lrelu result; bf16 cols>=74 garbage, never
//                             consumed by D: D reads ws cols <= 73 only)
// total 8064 dw = 31.5 KB -> 5 blocks/CU (20 waves, 62%).

#define TAPS 12
#define XS 0
#define XSS 44
#define VS 1848
#define VSS 44
#define WS 1848
#define WSS 84
#define ZS 5104
#define ZSS 40
#define LDS_DW 8064

__device__ __forceinline__ float bl(unsigned u){ return __uint_as_float(u << 16); }
__device__ __forceinline__ float bh(unsigned u){ return __uint_as_float(u & 0xffff0000u); }
__device__ __forceinline__ unsigned pk_bf2(float lo, float hi){
    __hip_bfloat16 a = __float2bfloat16(lo), b = __float2bfloat16(hi);
    unsigned short ua, ub;
    __builtin_memcpy(&ua, &a, 2); __builtin_memcpy(&ub, &b, 2);
    return (unsigned)ua | ((unsigned)ub << 16);
}

__global__ __launch_bounds__(256) void flrelu_fused(
    const float* __restrict__ x, const float* __restrict__ f, float* __restrict__ out)
{
    __shared__ float smem[LDS_DW];
    unsigned* smemu = reinterpret_cast<unsigned*>(smem);

    const int tid = threadIdx.x;
    const int nc  = blockIdx.y;
    const int ho0 = (blockIdx.x >> 2) * 32;
    const int wo0 = (blockIdx.x & 3) * 32;

    float fk[TAPS];
#pragma unroll
    for (int t = 0; t < TAPS; ++t) fk[t] = f[TAPS - 1 - t];

    const float* xin = x + (size_t)nc * (128 * 128);

    // ---- halo load: 42x42 fp32 ----
#pragma unroll
    for (int k = 0; k < 7; ++k) {
        int e = tid + 256 * k;
        if (e < 42 * 42) {
            int r = e / 42, c = e - r * 42;
            int gr = ho0 - 5 + r, gc = wo0 - 5 + c;
            float v = 0.f;
            if ((unsigned)gr < 128u && (unsigned)gc < 128u) v = xin[gr * 128 + gc];
            smem[XS + r * XSS + c] = v;
        }
    }
    __syncthreads();

    // ---- A: vertical up (fp32 -> VS). task = (col-pair cp<21, m-chunk mc<10), m=4mc+k ----
    if (tid < 210) {
        int cp = tid % 21, mc = tid / 21;
        int m0 = mc * 4;
        float2 v[9];
#pragma unroll
        for (int s = 0; s < 9; ++s) {
            int r = m0 + s; r = r < 42 ? r : 41;      // clamp; clamped rows only feed skipped m
            v[s] = *(const float2*)(smem + XS + r * XSS + 2 * cp);
        }
#pragma unroll
        for (int k = 0; k < 4; ++k) {
            int m = m0 + k;
            if (m < 37) {
                float ex = 0.f, ey = 0.f, ox = 0.f, oy = 0.f;
#pragma unroll
                for (int s = 0; s < 6; ++s) {
                    ex += fk[2*s+1] * v[k+s].x;  ey += fk[2*s+1] * v[k+s].y;
                    ox += fk[2*s]   * v[k+s].x;  oy += fk[2*s]   * v[k+s].y;
                }
                *(float2*)(smem + VS + (2*m)   * VSS + 2*cp) = make_float2(2.f*ex, 2.f*ey);
                *(float2*)(smem + VS + (2*m+1) * VSS + 2*cp) = make_float2(2.f*ox, 2.f*oy);
            }
        }
    }
    __syncthreads();

    // ---- B: horizontal up + lrelu (VS -> ZS bf16). task = (row i<74, 16-col chunk q<5) ----
#pragma unroll
    for (int it = 0; it < 2; ++it) {
        int task = tid + 256 * it;
        if (task < 370) {
            int q = task % 5, i = task / 5;
            const float* vp = smem + VS + i * VSS + 8 * q;
            float4 a  = *(const float4*)(vp);
            float4 b  = *(const float4*)(vp + 4);
            float4 cc = *(const float4*)(vp + 8);
            float c12 = vp[12];
            float c[13] = { a.x,a.y,a.z,a.w, b.x,b.y,b.z,b.w, cc.x,cc.y,cc.z,cc.w, c12 };
            unsigned pkz[8];
#pragma unroll
            for (int h = 0; h < 8; ++h) {            // j = 16q+2h (even), 16q+2h+1 (odd)
                float ze = 0.f, zo = 0.f;
#pragma unroll
                for (int s = 0; s < 6; ++s) {
                    ze += fk[2*s+1] * c[h+s];
                    zo += fk[2*s]   * c[h+s];
                }
                ze *= 2.f; zo *= 2.f;
                ze = ze >= 0.f ? ze : 0.01f * ze;
                zo = zo >= 0.f ? zo : 0.01f * zo;
                pkz[h] = pk_bf2(ze, zo);
            }
            unsigned* zp = smemu + ZS + i * ZSS + 8 * q;
            *(uint4*)(zp)     = make_uint4(pkz[0], pkz[1], pkz[2], pkz[3]);
            *(uint4*)(zp + 4) = make_uint4(pkz[4], pkz[5], pkz[6], pkz[7]);
        }
    }
    __syncthreads();

    // ---- C: vertical down (ZS -> WS fp32). task = (out-row ho<32, col-oct p8<10) ----
#pragma unroll
    for (int it = 0; it < 2; ++it) {
        int task = tid + 256 * it;
        if (task < 320) {
            int p8 = task % 10, ho = task / 10;
            const unsigned* zp = smemu + ZS + (2 * ho) * ZSS + 4 * p8;
            float a0 = 0.f, a1 = 0.f, a2 = 0.f, a3 = 0.f;
            float a4 = 0.f, a5 = 0.f, a6 = 0.f, a7 = 0.f;
#pragma unroll
            for (int u = 0; u < 12; ++u) {
                uint4 zr = *(const uint4*)(zp + u * ZSS);
                float w = fk[u];
                a0 += w * bl(zr.x); a1 += w * bh(zr.x);
                a2 += w * bl(zr.y); a3 += w * bh(zr.y);
                a4 += w * bl(zr.z); a5 += w * bh(zr.z);
                a6 += w * bl(zr.w); a7 += w * bh(zr.w);
            }
            float* wp = smem + WS + ho * WSS + 8 * p8;
            *(float4*)(wp)     = make_float4(a0, a1, a2, a3);
            *(float4*)(wp + 4) = make_float4(a4, a5, a6, a7);
        }
    }
    __syncthreads();

    // ---- D: horizontal down (WS -> global). task = (ho = tid>>3, col-quad w4 = tid&7) ----
    {
        int ho = tid >> 3, w4 = tid & 7;
        const float* wp = smem + WS + ho * WSS + 8 * w4;
        float4 r0 = *(const float4*)(wp);
        float4 r1 = *(const float4*)(wp + 4);
        float4 r2 = *(const float4*)(wp + 8);
        float4 r3 = *(const float4*)(wp + 12);
        float2 r4 = *(const float2*)(wp + 16);
        float w[18] = { r0.x,r0.y,r0.z,r0.w, r1.x,r1.y,r1.z,r1.w,
                        r2.x,r2.y,r2.z,r2.w, r3.x,r3.y,r3.z,r3.w, r4.x,r4.y };
        float o[4];
#pragma unroll
        for (int v = 0; v < 4; ++v) {
            float acc = 0.f;
#pragma unroll
            for (int t = 0; t < TAPS; ++t) acc += fk[t] * w[2 * v + t];
            o[v] = acc;
        }
        *(float4*)(out + ((size_t)nc * 128 + (ho0 + ho)) * 128 + wo0 + 4 * w4)
            = make_float4(o[0], o[1], o[2], o[3]);
    }
}

extern "C" void kernel_launch(void* const* d_in, const int* in_sizes, int n_in,
                              void* d_out, int out_size, void* d_ws, size_t ws_size,
                              hipStream_t stream) {
    const float* x = (const float*)d_in[0];
    const float* f = (const float*)d_in[1];
    float* out = (float*)d_out;
    dim3 grid(16, 1024);
    flrelu_fused<<<grid, 256, 0, stream>>>(x, f, out);
}